// Round 8
// baseline (234.086 us; speedup 1.0000x reference)
//
#include <hip/hip_runtime.h>
#include <hip/hip_bf16.h>

// GNN_65498251264428: 2-layer GraphConv + mean pool + Linear(64,1).
// N=100000 nodes, E=1000000 edges, F=H=64, G=128 graphs.
//
// Layer-2 algebraic collapse (layer 2 is linear):
//   out[g] = (u.T_g + v.S_g)/c_g + (w_lin.b2_rel + b_lin)
//   u = w2_rel^T w_lin, v = w2_root^T w_lin
//   S_g -> per-node scalar q_i = v.h1_i ; T_g -> per-edge w_e * p_{src}
//
// Round 8: gather was 43us bound by 256MB of per-edge fp32 x-row reads
// (113MB L2 miss). x pre-converted to bf16 (xh): rows 128B -> ~128MB cache
// reads, ~57MB fetch. Gather keeps R7's 16-lane/edge, 4-edges-in-flight
// structure (best Poisson-tail efficiency); dense reads xh directly
// (bit-identical to its previous f2bf(x)). Everything else unchanged from
// R7 (233us).

#define N_NODES 100000
#define N_EDGES 1000000
#define NGRAPHS 128
#define BN 512                              // nodes per bucket
#define NBUCK ((N_NODES + BN - 1) / BN)     // 196
#define FILL_T 16                           // edges per thread in bucket_fill
#define FILL_TILE (256 * FILL_T)            // 4096
#define FILL_NB ((N_EDGES + FILL_TILE - 1) / FILL_TILE)  // 245

typedef __attribute__((ext_vector_type(8))) short bf16x8;
typedef __attribute__((ext_vector_type(8))) unsigned short u16x8;
typedef __attribute__((ext_vector_type(4))) float f32x4;

__device__ __forceinline__ unsigned short f2bf(float f) {
    unsigned u = __float_as_uint(f);
    unsigned r = (u + 0x7FFFu + ((u >> 16) & 1u)) >> 16;  // RNE
    return (unsigned short)r;
}
__device__ __forceinline__ float bf2f(unsigned short h) {
    return __uint_as_float(((unsigned)h) << 16);
}

// ---- kernel 0: u, v, C + hi/lo bf16 split of W1rel/W1root ------------------
__global__ __launch_bounds__(256) void prep_kernel(
    const float* __restrict__ w1rel, const float* __restrict__ w1root,
    const float* __restrict__ w2rel, const float* __restrict__ w2root,
    const float* __restrict__ wlin, const float* __restrict__ b2rel,
    const float* __restrict__ blin, unsigned short* __restrict__ whirel,
    unsigned short* __restrict__ wlorel, unsigned short* __restrict__ whiroot,
    unsigned short* __restrict__ wloroot, float* __restrict__ u,
    float* __restrict__ v, float* __restrict__ C) {
    int tid = threadIdx.x;
    for (int i = tid; i < 4096; i += 256) {
        float a = w1rel[i];
        unsigned short hi = f2bf(a);
        whirel[i] = hi;
        wlorel[i] = f2bf(a - bf2f(hi));
        float b = w1root[i];
        unsigned short hb = f2bf(b);
        whiroot[i] = hb;
        wloroot[i] = f2bf(b - bf2f(hb));
    }
    if (tid < 64) {
        float uu = 0.f, vv = 0.f;
        for (int h = 0; h < 64; ++h) {
            float wl = wlin[h];
            uu += wl * w2rel[h * 64 + tid];
            vv += wl * w2root[h * 64 + tid];
        }
        u[tid] = uu;
        v[tid] = vv;
    }
    if (tid == 0) {
        float c = blin[0];
        for (int h = 0; h < 64; ++h) c += wlin[h] * b2rel[h];
        *C = c;
    }
}

// ---- kernel 0b: x -> bf16 copy (halves gather traffic) ---------------------
__global__ __launch_bounds__(256) void cvt_x_kernel(
    const float* __restrict__ x, unsigned short* __restrict__ xh, int n8) {
    int i = blockIdx.x * 256 + threadIdx.x;
    if (i >= n8) return;
    const float4* xp = (const float4*)x + (size_t)i * 2;
    float4 a = xp[0], b = xp[1];
    u16x8 o;
    o[0] = f2bf(a.x); o[1] = f2bf(a.y); o[2] = f2bf(a.z); o[3] = f2bf(a.w);
    o[4] = f2bf(b.x); o[5] = f2bf(b.y); o[6] = f2bf(b.z); o[7] = f2bf(b.w);
    *((u16x8*)xh + i) = o;
}

// ---- kernel 1: bucket histogram (LDS-aggregated) ---------------------------
__global__ __launch_bounds__(256) void bucket_hist(const int* __restrict__ ei,
                                                   int* __restrict__ bcount,
                                                   int E) {
    __shared__ int lh[NBUCK];
    int tid = threadIdx.x;
    for (int i = tid; i < NBUCK; i += 256) lh[i] = 0;
    __syncthreads();
    for (int e = blockIdx.x * 256 + tid; e < E; e += gridDim.x * 256)
        atomicAdd(&lh[ei[E + e] >> 9], 1);
    __syncthreads();
    for (int i = tid; i < NBUCK; i += 256) {
        int c = lh[i];
        if (c) atomicAdd(&bcount[i], c);
    }
}

// ---- kernel 2: scan 196 bucket counts -> boff, cursor ----------------------
__global__ void bucket_scan(const int* __restrict__ bcount,
                            int* __restrict__ boff, int* __restrict__ cursor) {
    __shared__ int s[256];
    int t = threadIdx.x;  // 256 threads
    int v = (t < NBUCK) ? bcount[t] : 0;
    s[t] = v;
    __syncthreads();
    for (int off = 1; off < 256; off <<= 1) {
        int x = (t >= off) ? s[t - off] : 0;
        __syncthreads();
        s[t] += x;
        __syncthreads();
    }
    if (t < NBUCK) {
        boff[t] = s[t] - v;
        cursor[t] = s[t] - v;
    }
    if (t == 255) boff[NBUCK] = s[255];  // == E
}

// ---- kernel 3: ranked bucket fill ------------------------------------------
// 4096-edge tile per block: LDS rank per bucket, one global reservation per
// (block,bucket), writes in ~21-record runs -> no write amplification.
// rec.x packs src | dlo<<17 (src < 2^17, dlo < 512).
__global__ __launch_bounds__(256) void bucket_fill(
    const int* __restrict__ ei, const float* __restrict__ ew,
    int* __restrict__ cursor, int2* __restrict__ ebuf, int E) {
    __shared__ int lh[NBUCK];
    __shared__ int gbase[NBUCK];
    int tid = threadIdx.x;
    for (int i = tid; i < NBUCK; i += 256) lh[i] = 0;
    __syncthreads();
    int base = blockIdx.x * FILL_TILE;
    int2 rec[FILL_T];
    int meta[FILL_T];
#pragma unroll
    for (int i = 0; i < FILL_T; ++i) {
        int e = base + i * 256 + tid;
        meta[i] = -1;
        if (e < E) {
            int src = ei[e];
            int dst = ei[E + e];
            int b = dst >> 9;
            int r = atomicAdd(&lh[b], 1);  // rank within (block,bucket)
            rec[i].x = src | ((dst & (BN - 1)) << 17);
            rec[i].y = __float_as_int(ew[e]);
            meta[i] = (b << 13) | r;  // r < 4096 fits 13 bits
        }
    }
    __syncthreads();
    for (int i = tid; i < NBUCK; i += 256) {
        int c = lh[i];
        gbase[i] = c ? atomicAdd(&cursor[i], c) : 0;
    }
    __syncthreads();
#pragma unroll
    for (int i = 0; i < FILL_T; ++i) {
        if (meta[i] >= 0) {
            int b = meta[i] >> 13;
            int r = meta[i] & 8191;
            ebuf[gbase[b] + r] = rec[i];
        }
    }
}

// ---- kernel 4: per-bucket degree scan -> row_ptr; place CSR with graph id --
// One block (512 thr) per bucket. csr.x = src | batch[node]<<17 (g < 128).
__global__ __launch_bounds__(512) void csr_build(
    const int* __restrict__ boff, const int2* __restrict__ ebuf,
    const int* __restrict__ batch, int* __restrict__ row_ptr,
    int2* __restrict__ csr, int N) {
    __shared__ int s[BN];
    int b = blockIdx.x;
    int t = threadIdx.x;
    int beg = boff[b], end = boff[b + 1];
    s[t] = 0;
    __syncthreads();
    for (int j = beg + t; j < end; j += 512)
        atomicAdd(&s[(ebuf[j].x >> 17) & (BN - 1)], 1);
    __syncthreads();
    int v = s[t];
    for (int off = 1; off < BN; off <<= 1) {
        int x = (t >= off) ? s[t - off] : 0;
        __syncthreads();
        s[t] += x;
        __syncthreads();
    }
    int excl = s[t] - v;
    int gidx = b * BN + t;
    if (gidx <= N) row_ptr[gidx] = beg + excl;  // covers row_ptr[N]=E too
    __syncthreads();
    s[t] = excl;  // becomes intra-bucket cursor
    __syncthreads();
    for (int j = beg + t; j < end; j += 512) {
        int2 rec = ebuf[j];
        int dlo = (rec.x >> 17) & (BN - 1);
        int g = batch[b * BN + dlo];  // L1-hot (1-2 lines per bucket)
        int r = atomicAdd(&s[dlo], 1);
        int2 o;
        o.x = (rec.x & 0x1FFFF) | (g << 17);  // src | graph<<17
        o.y = rec.y;                          // weight bits
        csr[beg + r] = o;
    }
}

// ---- kernel 5: gather  aggr[n] = sum_e w_e xh[src_e]  (bf16 in/out) --------
// 16 lanes per edge x 4 edges in parallel; ushort4 bf16 loads (128B rows);
// xor-reduce across the 4 groups.
__global__ __launch_bounds__(256) void gather_kernel(
    const unsigned short* __restrict__ xh, const int* __restrict__ row_ptr,
    const int2* __restrict__ csr, unsigned short* __restrict__ aggr, int N,
    int chunk) {
    int lane = threadIdx.x & 63;
    int wid = (blockIdx.x * blockDim.x + threadIdx.x) >> 6;
    int g = lane >> 4;   // edge slot within group of 4
    int c = lane & 15;   // ushort4 chunk of the 64-wide row
    int n0 = wid * chunk;
    int n1 = min(n0 + chunk, N);
    for (int node = n0; node < n1; ++node) {
        int beg = row_ptr[node], end = row_ptr[node + 1];
        float4 acc = {0.f, 0.f, 0.f, 0.f};
        for (int j0 = beg; j0 < end; j0 += 64) {
            int cnt = min(64, end - j0);
            int2 e = {0, 0};
            if (lane < cnt) e = csr[j0 + lane];
            for (int k = 0; k < cnt; k += 4) {
                int myk = k + g;
                int sj = __shfl(e.x, myk) & 0x1FFFF;
                float wj = __int_as_float(__shfl(e.y, myk));
                if (myk < cnt) {
                    ushort4 xv =
                        *(const ushort4*)(xh + (size_t)sj * 64 + c * 4);
                    acc.x += wj * bf2f(xv.x);
                    acc.y += wj * bf2f(xv.y);
                    acc.z += wj * bf2f(xv.z);
                    acc.w += wj * bf2f(xv.w);
                }
            }
        }
#pragma unroll
        for (int off = 16; off < 64; off <<= 1) {
            acc.x += __shfl_xor(acc.x, off);
            acc.y += __shfl_xor(acc.y, off);
            acc.z += __shfl_xor(acc.z, off);
            acc.w += __shfl_xor(acc.w, off);
        }
        if (lane < 16) {
            ushort4 o;
            o.x = f2bf(acc.x);
            o.y = f2bf(acc.y);
            o.z = f2bf(acc.z);
            o.w = f2bf(acc.w);
            *(ushort4*)(aggr + (size_t)node * 64 + c * 4) = o;
        }
    }
}

// ---- kernel 6: dense MFMA  t = aggr.Wrel^T + xh.Wroot^T + b; p,q -----------
// One wave per 16-node tile. A: m=lane&15, k=quad*8+j. D: col=lane&15 (=h),
// row=quad*4+reg (=node). Weights hi/lo split: A.(Whi+Wlo).
__global__ __launch_bounds__(256, 2) void dense_kernel(
    const unsigned short* __restrict__ aggr,
    const unsigned short* __restrict__ xh,
    const unsigned short* __restrict__ whirel,
    const unsigned short* __restrict__ wlorel,
    const unsigned short* __restrict__ whiroot,
    const unsigned short* __restrict__ wloroot,
    const float* __restrict__ b1rel, const float* __restrict__ u,
    const float* __restrict__ v, float* __restrict__ p, float* __restrict__ q,
    int N) {
    int lane = threadIdx.x & 63;
    int wave = (blockIdx.x << 2) + (threadIdx.x >> 6);
    int nb = wave * 16;
    if (nb >= N) return;
    int lo4 = lane & 15;
    int quad = lane >> 4;

    f32x4 acc[4];
#pragma unroll
    for (int t = 0; t < 4; ++t) acc[t] = (f32x4){0.f, 0.f, 0.f, 0.f};

    for (int s = 0; s < 2; ++s) {  // K-step: f in [s*32, s*32+32)
        bf16x8 Aa = *(const bf16x8*)(aggr + (size_t)(nb + lo4) * 64 + s * 32 +
                                     quad * 8);
        bf16x8 Ax = *(const bf16x8*)(xh + (size_t)(nb + lo4) * 64 + s * 32 +
                                     quad * 8);
#pragma unroll
        for (int t = 0; t < 4; ++t) {  // h-tile: h in [t*16, t*16+16)
            int off = (t * 16 + lo4) * 64 + s * 32 + quad * 8;
            bf16x8 bhr = *(const bf16x8*)(whirel + off);
            bf16x8 blr = *(const bf16x8*)(wlorel + off);
            bf16x8 bhx = *(const bf16x8*)(whiroot + off);
            bf16x8 blx = *(const bf16x8*)(wloroot + off);
            acc[t] = __builtin_amdgcn_mfma_f32_16x16x32_bf16(Aa, bhr, acc[t],
                                                             0, 0, 0);
            acc[t] = __builtin_amdgcn_mfma_f32_16x16x32_bf16(Aa, blr, acc[t],
                                                             0, 0, 0);
            acc[t] = __builtin_amdgcn_mfma_f32_16x16x32_bf16(Ax, bhx, acc[t],
                                                             0, 0, 0);
            acc[t] = __builtin_amdgcn_mfma_f32_16x16x32_bf16(Ax, blx, acc[t],
                                                             0, 0, 0);
        }
    }

    float pc[4] = {0.f, 0.f, 0.f, 0.f};
    float qc[4] = {0.f, 0.f, 0.f, 0.f};
#pragma unroll
    for (int t = 0; t < 4; ++t) {
        float bb = b1rel[t * 16 + lo4];
        float uu = u[t * 16 + lo4];
        float vv = v[t * 16 + lo4];
#pragma unroll
        for (int r = 0; r < 4; ++r) {
            float h1 = fmaxf(acc[t][r] + bb, 0.f);
            pc[r] += uu * h1;
            qc[r] += vv * h1;
        }
    }
#pragma unroll
    for (int off = 1; off < 16; off <<= 1) {
#pragma unroll
        for (int r = 0; r < 4; ++r) {
            pc[r] += __shfl_xor(pc[r], off);
            qc[r] += __shfl_xor(qc[r], off);
        }
    }
    if (lo4 == 0) {  // lanes 0,16,32,48: nodes nb+quad*4 .. +3
        f32x4 po = {pc[0], pc[1], pc[2], pc[3]};
        f32x4 qo = {qc[0], qc[1], qc[2], qc[3]};
        *(f32x4*)(p + nb + quad * 4) = po;
        *(f32x4*)(q + nb + quad * 4) = qo;
    }
}

// ---- kernel 7: T_g edge-flat over csr (graph id packed in csr.x) -----------
// 4 edges/lane; g monotone along csr -> per-lane curg accumulation, LDS
// flush on change, one global atomic per block per touched graph.
#define PT_EPT 4
#define PT_EPW (64 * PT_EPT)   // 256 edges per wave
__global__ __launch_bounds__(256) void pool_t_flat(
    const int2* __restrict__ csr, const float* __restrict__ p,
    float* __restrict__ gp, int E) {
    __shared__ float lgp[NGRAPHS];
    int tid = threadIdx.x;
    if (tid < NGRAPHS) lgp[tid] = 0.f;
    __syncthreads();
    int lane = tid & 63;
    int wid = (blockIdx.x * 256 + tid) >> 6;
    int base = wid * PT_EPW;
    float acc = 0.f;
    int curg = -1;
#pragma unroll
    for (int i = 0; i < PT_EPT; ++i) {
        int j = base + i * 64 + lane;
        if (j < E) {
            int2 e = csr[j];
            int g = ((unsigned)e.x) >> 17;
            float val = __int_as_float(e.y) * p[e.x & 0x1FFFF];
            if (g != curg) {
                if (curg >= 0) atomicAdd(&lgp[curg], acc);
                curg = g;
                acc = 0.f;
            }
            acc += val;
        }
    }
    if (curg >= 0) atomicAdd(&lgp[curg], acc);
    __syncthreads();
    if (tid < NGRAPHS) {
        float t = lgp[tid];
        if (t != 0.f) atomicAdd(&gp[tid], t);
    }
}

// ---- kernel 8: S_g / counts node-flat --------------------------------------
__global__ __launch_bounds__(256) void pool_s(const float* __restrict__ q,
                                              const int* __restrict__ batch,
                                              float* __restrict__ gq,
                                              float* __restrict__ gc, int N) {
    __shared__ float lgq[NGRAPHS], lgc[NGRAPHS];
    int tid = threadIdx.x;
    if (tid < NGRAPHS) {
        lgq[tid] = 0.f;
        lgc[tid] = 0.f;
    }
    __syncthreads();
    for (int i = blockIdx.x * 256 + tid; i < N; i += gridDim.x * 256) {
        int g = batch[i];
        atomicAdd(&lgq[g], q[i]);
        atomicAdd(&lgc[g], 1.f);
    }
    __syncthreads();
    if (tid < NGRAPHS) {
        if (lgc[tid] != 0.f) {
            atomicAdd(&gq[tid], lgq[tid]);
            atomicAdd(&gc[tid], lgc[tid]);
        }
    }
}

// ---- kernel 9: epilogue ----------------------------------------------------
__global__ void final_kernel(const float* __restrict__ gp,
                             const float* __restrict__ gq,
                             const float* __restrict__ gc,
                             const float* __restrict__ C,
                             float* __restrict__ out) {
    int g = threadIdx.x;  // 128 threads
    float c = fmaxf(gc[g], 1.0f);
    out[g] = (gp[g] + gq[g]) / c + *C;
}

extern "C" void kernel_launch(void* const* d_in, const int* in_sizes, int n_in,
                              void* d_out, int out_size, void* d_ws,
                              size_t ws_size, hipStream_t stream) {
    const float* x      = (const float*)d_in[0];   // [N,64]
    const int*   ei     = (const int*)d_in[1];     // [2,E]
    const float* ew     = (const float*)d_in[2];   // [E]
    const int*   batch  = (const int*)d_in[3];     // [N] sorted
    const float* w1rel  = (const float*)d_in[4];
    const float* b1rel  = (const float*)d_in[5];
    const float* w1root = (const float*)d_in[6];
    const float* w2rel  = (const float*)d_in[7];
    const float* b2rel  = (const float*)d_in[8];
    const float* w2root = (const float*)d_in[9];
    const float* wlin   = (const float*)d_in[10];
    const float* blin   = (const float*)d_in[11];
    float* out = (float*)d_out;

    // ---- workspace layout (~35 MB) ----
    // csr [0,8M) | aggr [8M,20.8M)  (ebuf aliases aggr: dead before gather
    // writes aggr) | weights/p/q/misc | row_ptr | xh (bf16 x copy).
    char* wsb = (char*)d_ws;
    int2* csr  = (int2*)wsb;                                   // 8 MB
    unsigned short* aggr = (unsigned short*)(wsb + (size_t)N_EDGES * 8);
    int2* ebuf = (int2*)aggr;                                  // alias
    char* tail = wsb + (size_t)N_EDGES * 8 + (size_t)N_NODES * 128;
    unsigned short* whirel  = (unsigned short*)tail;
    unsigned short* wlorel  = whirel + 4096;
    unsigned short* whiroot = wlorel + 4096;
    unsigned short* wloroot = whiroot + 4096;
    float* p  = (float*)(wloroot + 4096);                      // N
    float* q  = p + N_NODES;                                   // N
    float* u  = q + N_NODES;                                   // 64
    float* v  = u + 64;                                        // 64
    float* C  = v + 64;                                        // 1
    int*   bcount = (int*)(C + 1);                             // NBUCK
    float* gp = (float*)(bcount + NBUCK);                      // 128
    float* gq = gp + NGRAPHS;                                  // 128
    float* gc = gq + NGRAPHS;                                  // 128
    int*   boff   = (int*)(gc + NGRAPHS);                      // NBUCK+1
    int*   cursor = boff + (NBUCK + 1);                        // NBUCK
    int*   row_ptr = cursor + NBUCK;                           // N+1
    unsigned short* xh = (unsigned short*)(row_ptr + N_NODES + 2);  // N*64

    hipMemsetAsync(bcount, 0, (NBUCK + 3 * NGRAPHS) * sizeof(int), stream);

    prep_kernel<<<1, 256, 0, stream>>>(w1rel, w1root, w2rel, w2root, wlin,
                                       b2rel, blin, whirel, wlorel, whiroot,
                                       wloroot, u, v, C);
    cvt_x_kernel<<<(N_NODES * 64 / 8 + 255) / 256, 256, 0, stream>>>(
        x, xh, N_NODES * 64 / 8);

    bucket_hist<<<256, 256, 0, stream>>>(ei, bcount, N_EDGES);
    bucket_scan<<<1, 256, 0, stream>>>(bcount, boff, cursor);
    bucket_fill<<<FILL_NB, 256, 0, stream>>>(ei, ew, cursor, ebuf, N_EDGES);
    csr_build<<<NBUCK, 512, 0, stream>>>(boff, ebuf, batch, row_ptr, csr,
                                         N_NODES);

    {
        int blocks = 2048;  // 8192 waves, low VGPR -> deep latency hiding
        int waves = blocks * 4;
        int chunk = (N_NODES + waves - 1) / waves;  // 13
        gather_kernel<<<blocks, 256, 0, stream>>>(xh, row_ptr, csr, aggr,
                                                  N_NODES, chunk);
    }
    {
        int tiles = N_NODES / 16;                  // 6250
        int blocks = (tiles + 3) / 4;              // 1563
        dense_kernel<<<blocks, 256, 0, stream>>>(aggr, xh, whirel, wlorel,
                                                 whiroot, wloroot, b1rel, u, v,
                                                 p, q, N_NODES);
    }
    {
        int blocks = (N_EDGES + 4 * PT_EPW - 1) / (4 * PT_EPW);  // 977
        pool_t_flat<<<blocks, 256, 0, stream>>>(csr, p, gp, N_EDGES);
    }
    pool_s<<<196, 256, 0, stream>>>(q, batch, gq, gc, N_NODES);
    final_kernel<<<1, NGRAPHS, 0, stream>>>(gp, gq, gc, C, out);
}

// Round 9
// 223.092 us; speedup vs baseline: 1.0493x; 1.0493x over previous
//
#include <hip/hip_runtime.h>
#include <hip/hip_bf16.h>

// GNN_65498251264428: 2-layer GraphConv + mean pool + Linear(64,1).
// N=100000 nodes, E=1000000 edges, F=H=64, G=128 graphs.
//
// Layer-2 algebraic collapse (layer 2 is linear):
//   out[g] = (u.T_g + v.S_g)/c_g + (w_lin.b2_rel + b_lin)
//   u = w2_rel^T w_lin, v = w2_root^T w_lin
//   S_g -> per-node scalar q_i = v.h1_i ; T_g -> per-edge w_e * p_{src}
//
// Round 9: R8 was flat (bf16 halved gather bytes but kernel is
// latency/transaction-bound, cvt ate the gain). This round cuts aggregate
// overhead: gather+dense fused (per-wave 16-node tile, bf16 rows staged in
// LDS stride-72, inline MFMA -> no aggr HBM round-trip, one less launch),
// prep+cvt fused, pool_t+pool_s fused. 13 -> 9 launches.

#define N_NODES 100000
#define N_EDGES 1000000
#define NGRAPHS 128
#define BN 512                              // nodes per bucket
#define NBUCK ((N_NODES + BN - 1) / BN)     // 196
#define FILL_T 16                           // edges per thread in bucket_fill
#define FILL_TILE (256 * FILL_T)            // 4096
#define FILL_NB ((N_EDGES + FILL_TILE - 1) / FILL_TILE)  // 245
#define NTILES (N_NODES / 16)               // 6250 (exact)
#define AST 72                              // LDS row stride in shorts (144B: 16B-aligned frags)

typedef __attribute__((ext_vector_type(8))) short bf16x8;
typedef __attribute__((ext_vector_type(8))) unsigned short u16x8;
typedef __attribute__((ext_vector_type(4))) float f32x4;

__device__ __forceinline__ unsigned short f2bf(float f) {
    unsigned u = __float_as_uint(f);
    unsigned r = (u + 0x7FFFu + ((u >> 16) & 1u)) >> 16;  // RNE
    return (unsigned short)r;
}
__device__ __forceinline__ float bf2f(unsigned short h) {
    return __uint_as_float(((unsigned)h) << 16);
}

// ---- kernel 0: fused  x->bf16 cvt (blocks 0..3124) + prep (block 3125) -----
__global__ __launch_bounds__(256) void prep_cvt_kernel(
    const float* __restrict__ x, unsigned short* __restrict__ xh, int n8,
    const float* __restrict__ w1rel, const float* __restrict__ w1root,
    const float* __restrict__ w2rel, const float* __restrict__ w2root,
    const float* __restrict__ wlin, const float* __restrict__ b2rel,
    const float* __restrict__ blin, unsigned short* __restrict__ whirel,
    unsigned short* __restrict__ wlorel, unsigned short* __restrict__ whiroot,
    unsigned short* __restrict__ wloroot, float* __restrict__ u,
    float* __restrict__ v, float* __restrict__ C) {
    int tid = threadIdx.x;
    int i = blockIdx.x * 256 + tid;
    if (i < n8) {  // cvt part
        const float4* xp = (const float4*)x + (size_t)i * 2;
        float4 a = xp[0], b = xp[1];
        u16x8 o;
        o[0] = f2bf(a.x); o[1] = f2bf(a.y); o[2] = f2bf(a.z); o[3] = f2bf(a.w);
        o[4] = f2bf(b.x); o[5] = f2bf(b.y); o[6] = f2bf(b.z); o[7] = f2bf(b.w);
        *((u16x8*)xh + i) = o;
        return;
    }
    // prep part (one block past the cvt range)
    for (int k = tid; k < 4096; k += 256) {
        float a = w1rel[k];
        unsigned short hi = f2bf(a);
        whirel[k] = hi;
        wlorel[k] = f2bf(a - bf2f(hi));
        float b = w1root[k];
        unsigned short hb = f2bf(b);
        whiroot[k] = hb;
        wloroot[k] = f2bf(b - bf2f(hb));
    }
    if (tid < 64) {
        float uu = 0.f, vv = 0.f;
        for (int h = 0; h < 64; ++h) {
            float wl = wlin[h];
            uu += wl * w2rel[h * 64 + tid];
            vv += wl * w2root[h * 64 + tid];
        }
        u[tid] = uu;
        v[tid] = vv;
    }
    if (tid == 0) {
        float c = blin[0];
        for (int h = 0; h < 64; ++h) c += wlin[h] * b2rel[h];
        *C = c;
    }
}

// ---- kernel 1: bucket histogram (LDS-aggregated) ---------------------------
__global__ __launch_bounds__(256) void bucket_hist(const int* __restrict__ ei,
                                                   int* __restrict__ bcount,
                                                   int E) {
    __shared__ int lh[NBUCK];
    int tid = threadIdx.x;
    for (int i = tid; i < NBUCK; i += 256) lh[i] = 0;
    __syncthreads();
    for (int e = blockIdx.x * 256 + tid; e < E; e += gridDim.x * 256)
        atomicAdd(&lh[ei[E + e] >> 9], 1);
    __syncthreads();
    for (int i = tid; i < NBUCK; i += 256) {
        int c = lh[i];
        if (c) atomicAdd(&bcount[i], c);
    }
}

// ---- kernel 2: scan 196 bucket counts -> boff, cursor ----------------------
__global__ void bucket_scan(const int* __restrict__ bcount,
                            int* __restrict__ boff, int* __restrict__ cursor) {
    __shared__ int s[256];
    int t = threadIdx.x;  // 256 threads
    int v = (t < NBUCK) ? bcount[t] : 0;
    s[t] = v;
    __syncthreads();
    for (int off = 1; off < 256; off <<= 1) {
        int x = (t >= off) ? s[t - off] : 0;
        __syncthreads();
        s[t] += x;
        __syncthreads();
    }
    if (t < NBUCK) {
        boff[t] = s[t] - v;
        cursor[t] = s[t] - v;
    }
    if (t == 255) boff[NBUCK] = s[255];  // == E
}

// ---- kernel 3: ranked bucket fill ------------------------------------------
// 4096-edge tile per block: LDS rank per bucket, one global reservation per
// (block,bucket), writes in ~21-record runs -> no write amplification.
// rec.x packs src | dlo<<17 (src < 2^17, dlo < 512).
__global__ __launch_bounds__(256) void bucket_fill(
    const int* __restrict__ ei, const float* __restrict__ ew,
    int* __restrict__ cursor, int2* __restrict__ ebuf, int E) {
    __shared__ int lh[NBUCK];
    __shared__ int gbase[NBUCK];
    int tid = threadIdx.x;
    for (int i = tid; i < NBUCK; i += 256) lh[i] = 0;
    __syncthreads();
    int base = blockIdx.x * FILL_TILE;
    int2 rec[FILL_T];
    int meta[FILL_T];
#pragma unroll
    for (int i = 0; i < FILL_T; ++i) {
        int e = base + i * 256 + tid;
        meta[i] = -1;
        if (e < E) {
            int src = ei[e];
            int dst = ei[E + e];
            int b = dst >> 9;
            int r = atomicAdd(&lh[b], 1);  // rank within (block,bucket)
            rec[i].x = src | ((dst & (BN - 1)) << 17);
            rec[i].y = __float_as_int(ew[e]);
            meta[i] = (b << 13) | r;  // r < 4096 fits 13 bits
        }
    }
    __syncthreads();
    for (int i = tid; i < NBUCK; i += 256) {
        int c = lh[i];
        gbase[i] = c ? atomicAdd(&cursor[i], c) : 0;
    }
    __syncthreads();
#pragma unroll
    for (int i = 0; i < FILL_T; ++i) {
        if (meta[i] >= 0) {
            int b = meta[i] >> 13;
            int r = meta[i] & 8191;
            ebuf[gbase[b] + r] = rec[i];
        }
    }
}

// ---- kernel 4: per-bucket degree scan -> row_ptr; place CSR with graph id --
// One block (512 thr) per bucket. csr.x = src | batch[node]<<17 (g < 128).
__global__ __launch_bounds__(512) void csr_build(
    const int* __restrict__ boff, const int2* __restrict__ ebuf,
    const int* __restrict__ batch, int* __restrict__ row_ptr,
    int2* __restrict__ csr, int N) {
    __shared__ int s[BN];
    int b = blockIdx.x;
    int t = threadIdx.x;
    int beg = boff[b], end = boff[b + 1];
    s[t] = 0;
    __syncthreads();
    for (int j = beg + t; j < end; j += 512)
        atomicAdd(&s[(ebuf[j].x >> 17) & (BN - 1)], 1);
    __syncthreads();
    int v = s[t];
    for (int off = 1; off < BN; off <<= 1) {
        int x = (t >= off) ? s[t - off] : 0;
        __syncthreads();
        s[t] += x;
        __syncthreads();
    }
    int excl = s[t] - v;
    int gidx = b * BN + t;
    if (gidx <= N) row_ptr[gidx] = beg + excl;  // covers row_ptr[N]=E too
    __syncthreads();
    s[t] = excl;  // becomes intra-bucket cursor
    __syncthreads();
    for (int j = beg + t; j < end; j += 512) {
        int2 rec = ebuf[j];
        int dlo = (rec.x >> 17) & (BN - 1);
        int g = batch[b * BN + dlo];  // L1-hot (1-2 lines per bucket)
        int r = atomicAdd(&s[dlo], 1);
        int2 o;
        o.x = (rec.x & 0x1FFFF) | (g << 17);  // src | graph<<17
        o.y = rec.y;                          // weight bits
        csr[beg + r] = o;
    }
}

// ---- kernel 5: fused gather + MFMA dense -----------------------------------
// One wave per 16-node tile. Gather (16 lanes/edge, 4 edges in flight) lands
// each node's bf16 row in a per-wave LDS tile (stride 72 shorts: ushort4
// writes conflict-free, b128 frag reads 16B-aligned). Then inline MFMA
// (A: m=lane&15, k=quad*8+j; D: col=lane&15=h, row=quad*4+reg=node) with
// hi/lo-split weights; epilogue writes p,q. No aggr HBM round-trip, no
// __syncthreads (same-wave LDS RAW -> lgkmcnt).
__global__ __launch_bounds__(256) void gather_dense_kernel(
    const unsigned short* __restrict__ xh, const int* __restrict__ row_ptr,
    const int2* __restrict__ csr, const unsigned short* __restrict__ whirel,
    const unsigned short* __restrict__ wlorel,
    const unsigned short* __restrict__ whiroot,
    const unsigned short* __restrict__ wloroot,
    const float* __restrict__ b1rel, const float* __restrict__ u,
    const float* __restrict__ v, float* __restrict__ p, float* __restrict__ q,
    int ntiles) {
    __shared__ unsigned short arow[4][16 * AST];  // 4 waves x 2304B = 9216B
    int lane = threadIdx.x & 63;
    int wv = threadIdx.x >> 6;
    int wave = (blockIdx.x << 2) + wv;
    if (wave >= ntiles) return;  // whole-wave exit; no block barriers used
    unsigned short* my = &arow[wv][0];
    int nb = wave * 16;
    int g = lane >> 4;   // edge slot within group of 4
    int c = lane & 15;   // ushort4 chunk of the 64-wide row

    // ---- phase 1: gather 16 node rows into LDS ----
    for (int nl = 0; nl < 16; ++nl) {
        int node = nb + nl;
        int beg = row_ptr[node], end = row_ptr[node + 1];
        float4 acc = {0.f, 0.f, 0.f, 0.f};
        for (int j0 = beg; j0 < end; j0 += 64) {
            int cnt = min(64, end - j0);
            int2 e = {0, 0};
            if (lane < cnt) e = csr[j0 + lane];
            for (int k = 0; k < cnt; k += 4) {
                int myk = k + g;
                int sj = __shfl(e.x, myk) & 0x1FFFF;
                float wj = __int_as_float(__shfl(e.y, myk));
                if (myk < cnt) {
                    ushort4 xv =
                        *(const ushort4*)(xh + (size_t)sj * 64 + c * 4);
                    acc.x += wj * bf2f(xv.x);
                    acc.y += wj * bf2f(xv.y);
                    acc.z += wj * bf2f(xv.z);
                    acc.w += wj * bf2f(xv.w);
                }
            }
        }
#pragma unroll
        for (int off = 16; off < 64; off <<= 1) {
            acc.x += __shfl_xor(acc.x, off);
            acc.y += __shfl_xor(acc.y, off);
            acc.z += __shfl_xor(acc.z, off);
            acc.w += __shfl_xor(acc.w, off);
        }
        if (lane < 16) {
            ushort4 o;
            o.x = f2bf(acc.x);
            o.y = f2bf(acc.y);
            o.z = f2bf(acc.z);
            o.w = f2bf(acc.w);
            *(ushort4*)(my + nl * AST + c * 4) = o;  // banks 2c: conflict-free
        }
    }

    // ---- phase 2: MFMA dense on the 16-node tile ----
    int lo4 = lane & 15;
    int quad = lane >> 4;
    f32x4 acc4[4];
#pragma unroll
    for (int t = 0; t < 4; ++t) acc4[t] = (f32x4){0.f, 0.f, 0.f, 0.f};
#pragma unroll
    for (int s = 0; s < 2; ++s) {  // K-step: f in [s*32, s*32+32)
        bf16x8 Aa = *(const bf16x8*)(my + lo4 * AST + s * 32 + quad * 8);
        bf16x8 Ax = *(const bf16x8*)(xh + (size_t)(nb + lo4) * 64 + s * 32 +
                                     quad * 8);
#pragma unroll
        for (int t = 0; t < 4; ++t) {  // h-tile: h in [t*16, t*16+16)
            int off = (t * 16 + lo4) * 64 + s * 32 + quad * 8;
            bf16x8 bhr = *(const bf16x8*)(whirel + off);
            bf16x8 blr = *(const bf16x8*)(wlorel + off);
            bf16x8 bhx = *(const bf16x8*)(whiroot + off);
            bf16x8 blx = *(const bf16x8*)(wloroot + off);
            acc4[t] = __builtin_amdgcn_mfma_f32_16x16x32_bf16(Aa, bhr, acc4[t],
                                                              0, 0, 0);
            acc4[t] = __builtin_amdgcn_mfma_f32_16x16x32_bf16(Aa, blr, acc4[t],
                                                              0, 0, 0);
            acc4[t] = __builtin_amdgcn_mfma_f32_16x16x32_bf16(Ax, bhx, acc4[t],
                                                              0, 0, 0);
            acc4[t] = __builtin_amdgcn_mfma_f32_16x16x32_bf16(Ax, blx, acc4[t],
                                                              0, 0, 0);
        }
    }

    float pc[4] = {0.f, 0.f, 0.f, 0.f};
    float qc[4] = {0.f, 0.f, 0.f, 0.f};
#pragma unroll
    for (int t = 0; t < 4; ++t) {
        float bb = b1rel[t * 16 + lo4];
        float uu = u[t * 16 + lo4];
        float vv = v[t * 16 + lo4];
#pragma unroll
        for (int r = 0; r < 4; ++r) {
            float h1 = fmaxf(acc4[t][r] + bb, 0.f);
            pc[r] += uu * h1;
            qc[r] += vv * h1;
        }
    }
#pragma unroll
    for (int off = 1; off < 16; off <<= 1) {
#pragma unroll
        for (int r = 0; r < 4; ++r) {
            pc[r] += __shfl_xor(pc[r], off);
            qc[r] += __shfl_xor(qc[r], off);
        }
    }
    if (lo4 == 0) {  // lanes 0,16,32,48: nodes nb+quad*4 .. +3
        f32x4 po = {pc[0], pc[1], pc[2], pc[3]};
        f32x4 qo = {qc[0], qc[1], qc[2], qc[3]};
        *(f32x4*)(p + nb + quad * 4) = po;
        *(f32x4*)(q + nb + quad * 4) = qo;
    }
}

// ---- kernel 6: fused pooling -----------------------------------------------
// blocks [0, PT_NB): T_g edge-flat over csr (graph id in csr.x bits 17-23,
// monotone -> curg accumulate + LDS flush). blocks [PT_NB, PT_NB+PS_NB):
// S_g/count node-flat.
#define PT_EPT 4
#define PT_EPW (64 * PT_EPT)   // 256 edges per wave
#define PT_NB ((N_EDGES + 4 * PT_EPW - 1) / (4 * PT_EPW))  // 977
#define PS_NB 98
__global__ __launch_bounds__(256) void pool_both(
    const int2* __restrict__ csr, const float* __restrict__ p,
    const float* __restrict__ q, const int* __restrict__ batch,
    float* __restrict__ gp, float* __restrict__ gq, float* __restrict__ gc,
    int E, int N) {
    __shared__ float lbuf[2 * NGRAPHS];
    int tid = threadIdx.x;
    lbuf[tid] = 0.f;  // 256 threads zero 256 floats
    __syncthreads();
    if (blockIdx.x < PT_NB) {
        int lane = tid & 63;
        int wid = (blockIdx.x * 256 + tid) >> 6;
        int base = wid * PT_EPW;
        float acc = 0.f;
        int curg = -1;
#pragma unroll
        for (int i = 0; i < PT_EPT; ++i) {
            int j = base + i * 64 + lane;
            if (j < E) {
                int2 e = csr[j];
                int g = ((unsigned)e.x) >> 17;
                float val = __int_as_float(e.y) * p[e.x & 0x1FFFF];
                if (g != curg) {
                    if (curg >= 0) atomicAdd(&lbuf[curg], acc);
                    curg = g;
                    acc = 0.f;
                }
                acc += val;
            }
        }
        if (curg >= 0) atomicAdd(&lbuf[curg], acc);
        __syncthreads();
        if (tid < NGRAPHS) {
            float t = lbuf[tid];
            if (t != 0.f) atomicAdd(&gp[tid], t);
        }
    } else {
        int bid = blockIdx.x - PT_NB;
        for (int i = bid * 256 + tid; i < N; i += PS_NB * 256) {
            int g = batch[i];
            atomicAdd(&lbuf[g], q[i]);
            atomicAdd(&lbuf[NGRAPHS + g], 1.f);
        }
        __syncthreads();
        if (tid < NGRAPHS) {
            if (lbuf[NGRAPHS + tid] != 0.f) {
                atomicAdd(&gq[tid], lbuf[tid]);
                atomicAdd(&gc[tid], lbuf[NGRAPHS + tid]);
            }
        }
    }
}

// ---- kernel 7: epilogue ----------------------------------------------------
__global__ void final_kernel(const float* __restrict__ gp,
                             const float* __restrict__ gq,
                             const float* __restrict__ gc,
                             const float* __restrict__ C,
                             float* __restrict__ out) {
    int g = threadIdx.x;  // 128 threads
    float c = fmaxf(gc[g], 1.0f);
    out[g] = (gp[g] + gq[g]) / c + *C;
}

extern "C" void kernel_launch(void* const* d_in, const int* in_sizes, int n_in,
                              void* d_out, int out_size, void* d_ws,
                              size_t ws_size, hipStream_t stream) {
    const float* x      = (const float*)d_in[0];   // [N,64]
    const int*   ei     = (const int*)d_in[1];     // [2,E]
    const float* ew     = (const float*)d_in[2];   // [E]
    const int*   batch  = (const int*)d_in[3];     // [N] sorted
    const float* w1rel  = (const float*)d_in[4];
    const float* b1rel  = (const float*)d_in[5];
    const float* w1root = (const float*)d_in[6];
    const float* w2rel  = (const float*)d_in[7];
    const float* b2rel  = (const float*)d_in[8];
    const float* w2root = (const float*)d_in[9];
    const float* wlin   = (const float*)d_in[10];
    const float* blin   = (const float*)d_in[11];
    float* out = (float*)d_out;

    // ---- workspace layout ----
    // csr [0,8M) | ebuf [8M,16M) | weights/p/q/misc | row_ptr | xh.
    char* wsb = (char*)d_ws;
    int2* csr  = (int2*)wsb;                                   // 8 MB
    int2* ebuf = (int2*)(wsb + (size_t)N_EDGES * 8);           // 8 MB
    char* tail = wsb + (size_t)N_EDGES * 16;
    unsigned short* whirel  = (unsigned short*)tail;
    unsigned short* wlorel  = whirel + 4096;
    unsigned short* whiroot = wlorel + 4096;
    unsigned short* wloroot = whiroot + 4096;
    float* p  = (float*)(wloroot + 4096);                      // N
    float* q  = p + N_NODES;                                   // N
    float* u  = q + N_NODES;                                   // 64
    float* v  = u + 64;                                        // 64
    float* C  = v + 64;                                        // 1
    int*   bcount = (int*)(C + 1);                             // NBUCK
    float* gp = (float*)(bcount + NBUCK);                      // 128
    float* gq = gp + NGRAPHS;                                  // 128
    float* gc = gq + NGRAPHS;                                  // 128
    int*   boff   = (int*)(gc + NGRAPHS);                      // NBUCK+1
    int*   cursor = boff + (NBUCK + 1);                        // NBUCK
    int*   row_ptr = cursor + NBUCK;                           // N+1
    unsigned short* xh = (unsigned short*)(row_ptr + N_NODES + 2);  // N*64

    hipMemsetAsync(bcount, 0, (NBUCK + 3 * NGRAPHS) * sizeof(int), stream);

    int n8 = N_NODES * 64 / 8;  // 800000 cvt vector-groups
    prep_cvt_kernel<<<n8 / 256 + 1, 256, 0, stream>>>(
        x, xh, n8, w1rel, w1root, w2rel, w2root, wlin, b2rel, blin, whirel,
        wlorel, whiroot, wloroot, u, v, C);

    bucket_hist<<<256, 256, 0, stream>>>(ei, bcount, N_EDGES);
    bucket_scan<<<1, 256, 0, stream>>>(bcount, boff, cursor);
    bucket_fill<<<FILL_NB, 256, 0, stream>>>(ei, ew, cursor, ebuf, N_EDGES);
    csr_build<<<NBUCK, 512, 0, stream>>>(boff, ebuf, batch, row_ptr, csr,
                                         N_NODES);

    gather_dense_kernel<<<(NTILES + 3) / 4, 256, 0, stream>>>(
        xh, row_ptr, csr, whirel, wlorel, whiroot, wloroot, b1rel, u, v, p, q,
        NTILES);

    pool_both<<<PT_NB + PS_NB, 256, 0, stream>>>(csr, p, q, batch, gp, gq, gc,
                                                 N_EDGES, N_NODES);
    final_kernel<<<1, NGRAPHS, 0, stream>>>(gp, gq, gc, C, out);
}